// Round 6
// baseline (348.592 us; speedup 1.0000x reference)
//
#include <hip/hip_runtime.h>

// AttentionHead: B=8, N=2048, D=1024
// qkv = x @ W^T + b ; q,k,v split ; S = qk^T/32 ; P = softmax(S) ; out = P v
// GEMMs: 256x128 tile, BK=32, 8 waves (4Mx2N), TRIPLE-buffered LDS (72 KiB)
//   -> 2 blocks/CU co-resident (the round-5 lesson: 1 block/CU = every barrier
//   stalls the whole CU). Per phase (1 K-tile): read frags from buf t%3, stage
//   tile t+2 into buf (t+2)%3 (never the read buffer), uniform vmcnt(3)
//   (confirmed one phase + barrier before the reader), lgkmcnt(0) + setprio
//   around 16 MFMA, 2 barriers. Tail stages wrap te=t-1 (same buffer mod 3,
//   byte-identical rewrite). Swizzle: c ^= ((r>>1)&3)<<3 (16B granules in a
//   64B row), inverse-applied on the global source, linear gload_lds dest.
// Workspace layout (peak 230 MiB; bf16-S fallback peaks at 166 MiB):
//   [0,32MB) x_bf (later V^T) | [32,38) W_bf | [38,70) Q | [70,102) K
//   [102,134) V (dead after transpose) | [102,230) S f32 rows stride 2048,
//   P bf16 aliases rows (stride 4096 bf16)

#define AS1 __attribute__((address_space(1)))
#define AS3 __attribute__((address_space(3)))

typedef __bf16 bfrag  __attribute__((ext_vector_type(8)));
typedef float  ffrag  __attribute__((ext_vector_type(4)));
typedef __bf16 bf16x4 __attribute__((ext_vector_type(4)));
typedef __bf16 bf16x8 __attribute__((ext_vector_type(8)));
typedef unsigned short ushort8v __attribute__((ext_vector_type(8)));

// ---------------- f32 -> bf16 convert, x4 vectorized ----------------
__global__ __launch_bounds__(256) void cvt_f32_bf16(const float* __restrict__ in,
                                                    __bf16* __restrict__ out, int n4) {
  int i = blockIdx.x * blockDim.x + threadIdx.x;
  int stride = gridDim.x * blockDim.x;
  for (; i < n4; i += stride) {
    float4 v = ((const float4*)in)[i];
    bf16x4 o;
    o[0] = (__bf16)v.x; o[1] = (__bf16)v.y; o[2] = (__bf16)v.z; o[3] = (__bf16)v.w;
    ((bf16x4*)out)[i] = o;
  }
}

// =================== 256x128 BK=32 triple-buffer GEMM mainloop ===================
// C[m][o] = sum_k A[m][k] * B[o][k]  (both K-major, B^T form)
// 512 threads = 8 waves: wr = wid>>1 (0..3) M-block, wc = wid&1 (0..1) N-block.
// Per wave 64x64 output -> acc[4][4] (64 VGPR).
// LDS buffer (24 KiB = 12288 elems): A[256][32] @0, B[128][32] @8192. 3 bufs.
// Stage: 3 gload_lds(16B)/thread per tile {A rows 0-127, A rows 128-255, B}.

__device__ __forceinline__ void stage_tile(
    const __bf16* __restrict__ A, const __bf16* __restrict__ B,
    int lda, int ldb, __bf16* lds, int bufElem, int kt, int sr, int sc, int ldsOff) {
  __builtin_amdgcn_global_load_lds((AS1 void*)(A + (size_t)sr * lda + kt + sc),
                                   (AS3 void*)(lds + bufElem + ldsOff), 16, 0, 0);
  __builtin_amdgcn_global_load_lds((AS1 void*)(A + (size_t)(128 + sr) * lda + kt + sc),
                                   (AS3 void*)(lds + bufElem + 4096 + ldsOff), 16, 0, 0);
  __builtin_amdgcn_global_load_lds((AS1 void*)(B + (size_t)sr * ldb + kt + sc),
                                   (AS3 void*)(lds + bufElem + 8192 + ldsOff), 16, 0, 0);
}

__device__ __forceinline__ void gemm256x128_mainloop(
    const __bf16* __restrict__ Atile, const __bf16* __restrict__ Btile,
    int lda, int ldb, int K, __bf16* lds, ffrag acc[4][4]) {
  const int tid  = threadIdx.x;
  const int lane = tid & 63;
  const int wid  = tid >> 6;
  const int wr   = wid >> 1, wc = wid & 1;
  const int fr   = lane & 15;
  const int fk   = (lane >> 4) * 8;              // k-base 0,8,16,24
  const int ck   = fk ^ (((fr >> 1) & 3) << 3);  // swizzled frag col (elems)
  const int aRow = (wr * 64 + fr) * 32;          // A region elem offset (row base)
  const int bRow = 8192 + (wc * 64 + fr) * 32;   // B region elem offset
  const int sr   = tid >> 2;                     // staging row 0..127
  const int sc   = ((tid & 3) * 8) ^ (((sr >> 1) & 3) << 3);  // inv-swz src col
  const int ldsOff = tid * 8;                    // linear dest within 4096-elem half
  const int nT = K >> 5;

  // prologue: stage tiles 0,1; confirm tile 0 (3 oldest); barrier.
  stage_tile(Atile, Btile, lda, ldb, lds, 0,     0,  sr, sc, ldsOff);
  stage_tile(Atile, Btile, lda, ldb, lds, 12288, 32, sr, sc, ldsOff);
  asm volatile("s_waitcnt vmcnt(3)" ::: "memory");
  __builtin_amdgcn_s_barrier();

  int bi = 0;   // read buffer index (t % 3)
  int si = 2;   // stage buffer index ((t+2) % 3)
#pragma unroll 1
  for (int t = 0; t < nT; ++t) {
    const int bo = bi * 12288;
    bfrag a[4], b[4];
#pragma unroll
    for (int m = 0; m < 4; ++m) a[m] = *(const bfrag*)&lds[bo + aRow + m * 512 + ck];
#pragma unroll
    for (int n = 0; n < 4; ++n) b[n] = *(const bfrag*)&lds[bo + bRow + n * 512 + ck];
    const int te = (t + 2 < nT) ? (t + 2) : (t - 1);   // tail: same buf mod 3, same bytes
    stage_tile(Atile, Btile, lda, ldb, lds, si * 12288, te * 32, sr, sc, ldsOff);
    asm volatile("s_waitcnt vmcnt(3)" ::: "memory");   // tile t+1 confirmed for next phase
    __builtin_amdgcn_sched_barrier(0);
    __builtin_amdgcn_s_barrier();
    asm volatile("s_waitcnt lgkmcnt(0)" ::: "memory");
    __builtin_amdgcn_sched_barrier(0);
    __builtin_amdgcn_s_setprio(1);
#pragma unroll
    for (int m = 0; m < 4; ++m)
#pragma unroll
      for (int n = 0; n < 4; ++n)
        acc[m][n] = __builtin_amdgcn_mfma_f32_16x16x32_bf16(a[m], b[n], acc[m][n], 0, 0, 0);
    __builtin_amdgcn_s_setprio(0);
    __builtin_amdgcn_sched_barrier(0);
    __builtin_amdgcn_s_barrier();
    __builtin_amdgcn_sched_barrier(0);
    bi = (bi == 2) ? 0 : bi + 1;
    si = (si == 2) ? 0 : si + 1;
  }
}

#define ACC_ZERO()                                                             \
  ffrag acc[4][4];                                                             \
  _Pragma("unroll") for (int m = 0; m < 4; ++m)                                \
  _Pragma("unroll") for (int n = 0; n < 4; ++n) acc[m][n] = (ffrag)(0.0f);

// Epilogue: row = brow + wr*64 + m*16 + (lane>>4)*4 + r ; col = bcol + wc*64 + n*16 + (lane&15)

// ---------------- kernel 1: qkv projection ----------------
__global__ __launch_bounds__(512, 4) void qkv_gemm(
    const __bf16* __restrict__ Abf, const __bf16* __restrict__ Wbf,
    const float* __restrict__ bias,
    __bf16* __restrict__ Q, __bf16* __restrict__ Ko, __bf16* __restrict__ V) {
  __shared__ __bf16 lds[36864];
  ACC_ZERO();
  int bid = (int)blockIdx.x;
  bid = (bid & 7) * 192 + (bid >> 3);         // XCD swizzle (1536 % 8 == 0, bijective)
  const int brow = (bid / 24) * 256;
  const int bcol = (bid % 24) * 128;
  gemm256x128_mainloop(Abf + (size_t)brow * 1024, Wbf + (size_t)bcol * 1024,
                       1024, 1024, 1024, lds, acc);
  const int lane = threadIdx.x & 63, wid = threadIdx.x >> 6;
  const int wr = wid >> 1, wc = wid & 1;
  const int region = bcol >> 10;              // 0=Q,1=K,2=V (128-tile within one region)
  __bf16* dst = region == 0 ? Q : (region == 1 ? Ko : V);
  const float scale = region == 0 ? 0.03125f : 1.0f;   // fold 1/sqrt(1024) into Q
#pragma unroll
  for (int n = 0; n < 4; ++n) {
    const int col = bcol + wc * 64 + n * 16 + (lane & 15);
    const int o = col & 1023;
    const float bv = bias[col];
#pragma unroll
    for (int m = 0; m < 4; ++m)
#pragma unroll
      for (int r = 0; r < 4; ++r) {
        const int mg = brow + wr * 64 + m * 16 + (lane >> 4) * 4 + r;
        dst[(size_t)mg * 1024 + o] = (__bf16)((acc[m][n][r] + bv) * scale);
      }
  }
}

// ---------------- kernel 2: V [b][n][d] -> Vt [b][d][n] ----------------
__global__ __launch_bounds__(256) void transpose_v(const ushort* __restrict__ V,
                                                   ushort* __restrict__ Vt) {
  __shared__ ushort t[64][72];
  const int b = blockIdx.z;
  const int n0 = blockIdx.x * 64, d0 = blockIdx.y * 64;
  const int tid = threadIdx.x;
  const ushort* Vb = V + (size_t)b * 2048 * 1024;
  ushort* Vtb = Vt + (size_t)b * 1024 * 2048;
#pragma unroll
  for (int it = 0; it < 2; ++it) {
    int n = it * 32 + (tid >> 3);
    int d8 = (tid & 7) * 8;
    ushort8v v = *(const ushort8v*)&Vb[(size_t)(n0 + n) * 1024 + d0 + d8];
#pragma unroll
    for (int j = 0; j < 8; ++j) t[d8 + j][n] = v[j];
  }
  __syncthreads();
#pragma unroll
  for (int it = 0; it < 2; ++it) {
    int d = it * 32 + (tid >> 3);
    int n8 = (tid & 7) * 8;
    ushort8v v = *(const ushort8v*)&t[d][n8];
    *(ushort8v*)&Vtb[(size_t)(d0 + d) * 2048 + n0 + n8] = v;
  }
}

// ---------------- kernel 3: scores S = Q K^T (Q pre-scaled) ----------------
template <typename ST>
__global__ __launch_bounds__(512, 4) void scores_gemm(const __bf16* __restrict__ Q,
                                                      const __bf16* __restrict__ Kb,
                                                      ST* __restrict__ S) {
  __shared__ __bf16 lds[36864];
  ACC_ZERO();
  const int z = blockIdx.z;
  const int brow = blockIdx.x * 256, bcol = blockIdx.y * 128;
  gemm256x128_mainloop(Q + (size_t)z * 2048 * 1024 + (size_t)brow * 1024,
                       Kb + (size_t)z * 2048 * 1024 + (size_t)bcol * 1024,
                       1024, 1024, 1024, lds, acc);
  const int lane = threadIdx.x & 63, wid = threadIdx.x >> 6;
  const int wr = wid >> 1, wc = wid & 1;
#pragma unroll
  for (int n = 0; n < 4; ++n) {
    const int o = bcol + wc * 64 + n * 16 + (lane & 15);
#pragma unroll
    for (int m = 0; m < 4; ++m)
#pragma unroll
      for (int r = 0; r < 4; ++r) {
        const int mg = brow + wr * 64 + m * 16 + (lane >> 4) * 4 + r;
        S[((size_t)(z * 2048 + mg)) * 2048 + o] = (ST)acc[m][n][r];
      }
  }
}

// ---------------- kernel 4a: row softmax, S f32 -> P bf16 (aliased rows) ----
__global__ __launch_bounds__(256) void softmax_f32(const float* S, __bf16* P) {
  const int row = blockIdx.x;
  const float* s = S + (size_t)row * 2048;
  __bf16* p = P + (size_t)row * 4096;
  const int t = threadIdx.x;
  float4 v0 = *(const float4*)&s[t * 4];
  float4 v1 = *(const float4*)&s[1024 + t * 4];
  float m = fmaxf(fmaxf(fmaxf(v0.x, v0.y), fmaxf(v0.z, v0.w)),
                  fmaxf(fmaxf(v1.x, v1.y), fmaxf(v1.z, v1.w)));
#pragma unroll
  for (int off = 32; off; off >>= 1) m = fmaxf(m, __shfl_xor(m, off, 64));
  __shared__ float redm[4];
  if ((t & 63) == 0) redm[t >> 6] = m;
  __syncthreads();
  m = fmaxf(fmaxf(redm[0], redm[1]), fmaxf(redm[2], redm[3]));
  float e[8];
  e[0] = __expf(v0.x - m); e[1] = __expf(v0.y - m);
  e[2] = __expf(v0.z - m); e[3] = __expf(v0.w - m);
  e[4] = __expf(v1.x - m); e[5] = __expf(v1.y - m);
  e[6] = __expf(v1.z - m); e[7] = __expf(v1.w - m);
  float sum = ((e[0] + e[1]) + (e[2] + e[3])) + ((e[4] + e[5]) + (e[6] + e[7]));
#pragma unroll
  for (int off = 32; off; off >>= 1) sum += __shfl_xor(sum, off, 64);
  __shared__ float reds[4];
  if ((t & 63) == 0) reds[t >> 6] = sum;
  __syncthreads();
  float inv = 1.0f / (((reds[0] + reds[1]) + (reds[2] + reds[3])));
  bf16x4 o0, o1;
#pragma unroll
  for (int j = 0; j < 4; ++j) { o0[j] = (__bf16)(e[j] * inv); o1[j] = (__bf16)(e[4 + j] * inv); }
  *(bf16x4*)&p[t * 4] = o0;
  *(bf16x4*)&p[1024 + t * 4] = o1;
}

// ---------------- kernel 4b: in-place bf16 softmax (fallback path) ----------
__global__ __launch_bounds__(256) void softmax_bf16(__bf16* S) {
  const int row = blockIdx.x;
  __bf16* s = S + (size_t)row * 2048;
  const int t = threadIdx.x;
  bf16x8 v = *(const bf16x8*)&s[t * 8];
  float f[8];
#pragma unroll
  for (int j = 0; j < 8; ++j) f[j] = (float)v[j];
  float m = fmaxf(fmaxf(fmaxf(f[0], f[1]), fmaxf(f[2], f[3])),
                  fmaxf(fmaxf(f[4], f[5]), fmaxf(f[6], f[7])));
#pragma unroll
  for (int off = 32; off; off >>= 1) m = fmaxf(m, __shfl_xor(m, off, 64));
  __shared__ float redm[4];
  if ((t & 63) == 0) redm[t >> 6] = m;
  __syncthreads();
  m = fmaxf(fmaxf(redm[0], redm[1]), fmaxf(redm[2], redm[3]));
  float e[8], sum = 0.f;
#pragma unroll
  for (int j = 0; j < 8; ++j) { e[j] = __expf(f[j] - m); sum += e[j]; }
#pragma unroll
  for (int off = 32; off; off >>= 1) sum += __shfl_xor(sum, off, 64);
  __shared__ float reds[4];
  if ((t & 63) == 0) reds[t >> 6] = sum;
  __syncthreads();
  float inv = 1.0f / (((reds[0] + reds[1]) + (reds[2] + reds[3])));
  bf16x8 o;
#pragma unroll
  for (int j = 0; j < 8; ++j) o[j] = (__bf16)(e[j] * inv);
  *(bf16x8*)&s[t * 8] = o;
}

// ---------------- kernel 5: out = P @ V  (via Vt, B^T form) ----------------
__global__ __launch_bounds__(512, 4) void pv_gemm(const __bf16* __restrict__ P,
                                                  const __bf16* __restrict__ Vt,
                                                  float* __restrict__ O, int lda) {
  __shared__ __bf16 lds[36864];
  ACC_ZERO();
  const int z = blockIdx.z;
  const int brow = blockIdx.x * 256, bcol = blockIdx.y * 128;
  gemm256x128_mainloop(P + (size_t)(z * 2048 + brow) * lda,
                       Vt + (size_t)z * 1024 * 2048 + (size_t)bcol * 2048,
                       lda, 2048, 2048, lds, acc);
  const int lane = threadIdx.x & 63, wid = threadIdx.x >> 6;
  const int wr = wid >> 1, wc = wid & 1;
#pragma unroll
  for (int n = 0; n < 4; ++n) {
    const int o = bcol + wc * 64 + n * 16 + (lane & 15);
#pragma unroll
    for (int m = 0; m < 4; ++m)
#pragma unroll
      for (int r = 0; r < 4; ++r) {
        const int mg = brow + wr * 64 + m * 16 + (lane >> 4) * 4 + r;
        O[((size_t)(z * 2048 + mg)) * 1024 + o] = acc[m][n][r];
      }
  }
}

extern "C" void kernel_launch(void* const* d_in, const int* in_sizes, int n_in,
                              void* d_out, int out_size, void* d_ws, size_t ws_size,
                              hipStream_t stream) {
  (void)in_sizes; (void)n_in; (void)out_size;
  const float* x    = (const float*)d_in[0];
  const float* W    = (const float*)d_in[1];
  const float* bias = (const float*)d_in[2];
  float* out = (float*)d_out;
  char* ws = (char*)d_ws;
  const size_t MB = 1u << 20;
  __bf16* x_bf = (__bf16*)(ws + 0);
  __bf16* W_bf = (__bf16*)(ws + 32 * MB);
  __bf16* Qb   = (__bf16*)(ws + 38 * MB);
  __bf16* Kb   = (__bf16*)(ws + 70 * MB);
  __bf16* Vb   = (__bf16*)(ws + 102 * MB);
  void*   Sbase = (void*)(ws + 102 * MB);    // overwrites V after transpose_v
  __bf16* Vt   = (__bf16*)(ws + 0);          // reuses x_bf after qkv_gemm

  cvt_f32_bf16<<<2048, 256, 0, stream>>>(x, x_bf, 16777216 / 4);
  cvt_f32_bf16<<<1024, 256, 0, stream>>>(W, W_bf, 3145728 / 4);
  qkv_gemm<<<1536, 512, 0, stream>>>(x_bf, W_bf, bias, Qb, Kb, Vb);
  transpose_v<<<dim3(32, 16, 8), 256, 0, stream>>>((const ushort*)Vb, (ushort*)Vt);

  if (ws_size >= 230 * MB) {
    float*  S = (float*)Sbase;
    __bf16* P = (__bf16*)Sbase;
    scores_gemm<float><<<dim3(8, 16, 8), 512, 0, stream>>>(Qb, Kb, S);
    softmax_f32<<<16384, 256, 0, stream>>>(S, P);
    pv_gemm<<<dim3(8, 8, 8), 512, 0, stream>>>(P, Vt, out, 4096);
  } else {
    __bf16* S = (__bf16*)Sbase;
    scores_gemm<__bf16><<<dim3(8, 16, 8), 512, 0, stream>>>(Qb, Kb, S);
    softmax_bf16<<<16384, 256, 0, stream>>>(S);
    pv_gemm<<<dim3(8, 8, 8), 512, 0, stream>>>(S, Vt, out, 2048);
  }
}

// Round 7
// 307.371 us; speedup vs baseline: 1.1341x; 1.1341x over previous
//
#include <hip/hip_runtime.h>

// AttentionHead: B=8, N=2048, D=1024
// qkv = x @ W^T + b ; q,k,v split ; S = qk^T/32 ; P = softmax(S) ; out = P v
// Pipeline: cvt -> qkv_gemm256 (writes Q, K, and V^T directly) ->
//           scores_gemm256 (bf16 S) -> softmax_bf16 (in-place) -> pv_gemm256
// GEMMs: 256x256 4-phase schedule (round-5 verified):
//   P1: read b[4][2]+a0[4][2] from buf0, MFMA qa=0 | P2: read a1[4][2], reuse b, qa=1
//   P3/P4: same on buf1. 24 ds_read_b128 per wave per K-tile (the minimum).
//   Stage slots: P1:A1(t+1) P2:{B0,B1,A0}(t+2) P3:A1(t+2) P4:{B0,B1,A0}(t+3).
//   Uniform vmcnt(8); every staged region completes one phase+barrier before its
//   reader; every LDS region retires (lgkmcnt(0)+barrier) before re-stage.
// Workspace layout (peak 198 MiB):
//   [0,32MB)    x_bf          [32,38MB)  W_bf
//   [38,70MB)   Q bf16        [70,102MB) K bf16
//   [102,166MB) S bf16 rows stride 2048 (softmax in-place -> P)
//   [166,198MB) Vt bf16 [b][d][n]

#define AS1 __attribute__((address_space(1)))
#define AS3 __attribute__((address_space(3)))

typedef __bf16 bfrag  __attribute__((ext_vector_type(8)));
typedef float  ffrag  __attribute__((ext_vector_type(4)));
typedef __bf16 bf16x4 __attribute__((ext_vector_type(4)));
typedef __bf16 bf16x8 __attribute__((ext_vector_type(8)));

// ---------------- f32 -> bf16 convert, x4 vectorized ----------------
__global__ __launch_bounds__(256) void cvt_f32_bf16(const float* __restrict__ in,
                                                    __bf16* __restrict__ out, int n4) {
  int i = blockIdx.x * blockDim.x + threadIdx.x;
  int stride = gridDim.x * blockDim.x;
  for (; i < n4; i += stride) {
    float4 v = ((const float4*)in)[i];
    bf16x4 o;
    o[0] = (__bf16)v.x; o[1] = (__bf16)v.y; o[2] = (__bf16)v.z; o[3] = (__bf16)v.w;
    ((bf16x4*)out)[i] = o;
  }
}

// =================== 256x256 4-phase GEMM mainloop (round-5, verified) ========
__device__ __forceinline__ void stage_half(
    const __bf16* __restrict__ Atile, const __bf16* __restrict__ Btile,
    int lda, int ldb, int nT, __bf16* lds, int tid, int t, int h) {
  const int te = (t < nT) ? t : (t - 2);   // same parity -> same buffer, same data
  const int kt = te * 64;
  const __bf16* src = (h < 2) ? Atile : Btile;
  const int ld = (h < 2) ? lda : ldb;
  const int row0 = (h & 1) * 128;
  __bf16* dst = lds + (te & 1) * 32768 + h * 8192;
#pragma unroll
  for (int l = 0; l < 2; ++l) {
    const int y = l * 4096 + tid * 8;                  // linear LDS dest (uniform base + lane*16B)
    const int r = y >> 6;                              // row within half (0..127)
    const int c = ((tid & 7) * 8) ^ ((r & 7) << 3);    // inverse-swizzled source col
    __builtin_amdgcn_global_load_lds((AS1 void*)(src + (size_t)(row0 + r) * ld + kt + c),
                                     (AS3 void*)(dst + y), 16, 0, 0);
  }
}

__device__ __forceinline__ void rd_b(const __bf16* lds, int bufoff, int bRowBase,
                                     int ck0, int ck1, bfrag b[4][2]) {
#pragma unroll
  for (int j = 0; j < 4; ++j) {
    const int off = bufoff + bRowBase + (j >> 1) * 8192 + (j & 1) * 1024;
    b[j][0] = *(const bfrag*)&lds[off + ck0];
    b[j][1] = *(const bfrag*)&lds[off + ck1];
  }
}

template <int QA>
__device__ __forceinline__ void rd_a(const __bf16* lds, int bufoff, int aRowBase,
                                     int ck0, int ck1, bfrag a[4][2]) {
#pragma unroll
  for (int m = 0; m < 4; ++m) {
    const int off = bufoff + aRowBase + QA * 8192 + m * 1024;
    a[m][0] = *(const bfrag*)&lds[off + ck0];
    a[m][1] = *(const bfrag*)&lds[off + ck1];
  }
}

template <int QA>
__device__ __forceinline__ void mfma_q(const bfrag a[4][2], const bfrag b[4][2],
                                       ffrag acc[8][4]) {
#pragma unroll
  for (int m = 0; m < 4; ++m)
#pragma unroll
    for (int j = 0; j < 4; ++j)
#pragma unroll
      for (int ks = 0; ks < 2; ++ks)
        acc[QA * 4 + m][j] = __builtin_amdgcn_mfma_f32_16x16x32_bf16(
            a[m][ks], b[j][ks], acc[QA * 4 + m][j], 0, 0, 0);
}

#define SYNC_MFMA(QA)                                                          \
    asm volatile("s_waitcnt vmcnt(8)" ::: "memory");                           \
    __builtin_amdgcn_sched_barrier(0);                                         \
    __builtin_amdgcn_s_barrier();                                              \
    asm volatile("s_waitcnt lgkmcnt(0)" ::: "memory");                         \
    __builtin_amdgcn_sched_barrier(0);                                         \
    __builtin_amdgcn_s_setprio(1);                                             \
    mfma_q<QA>(a, b, acc);                                                     \
    __builtin_amdgcn_s_setprio(0);                                             \
    __builtin_amdgcn_sched_barrier(0);                                         \
    __builtin_amdgcn_s_barrier();                                              \
    __builtin_amdgcn_sched_barrier(0);

#define STG(T, H) stage_half(Atile, Btile, lda, ldb, nT, lds, tid, (T), (H))

__device__ __forceinline__ void gemm256_mainloop(
    const __bf16* __restrict__ Atile, const __bf16* __restrict__ Btile,
    int lda, int ldb, int K, __bf16* lds, ffrag acc[8][4]) {
  const int tid  = threadIdx.x;
  const int lane = tid & 63;
  const int wid  = tid >> 6;
  const int wr   = wid >> 2, wc = wid & 3;
  const int fr   = lane & 15;
  const int fk   = (lane >> 4) * 8;
  const int swz  = (fr & 7) << 3;
  const int ck0  = fk ^ swz;            // ks=0 frag col (swizzled)
  const int ck1  = (32 + fk) ^ swz;     // ks=1
  const int aRowBase = (wr * 64 + fr) * 64;
  const int bRowBase = 16384 + (wc * 32 + fr) * 64;
  const int nT = K >> 6;

  // prologue: t0 {B0,B1,A0,A1}; t1 {B0,B1,A0}. vmcnt(8) -> t0.{B0,B1,A0} done.
  STG(0, 2); STG(0, 3); STG(0, 0); STG(0, 1);
  STG(1, 2); STG(1, 3); STG(1, 0);
  asm volatile("s_waitcnt vmcnt(8)" ::: "memory");
  __builtin_amdgcn_s_barrier();

  const int nIter = nT >> 1;
#pragma unroll 1
  for (int i = 0; i < nIter; ++i) {
    const int t1 = 2 * i + 1, t2 = 2 * i + 2, t3 = 2 * i + 3;
    bfrag a[4][2], b[4][2];
    rd_b(lds, 0, bRowBase, ck0, ck1, b);
    rd_a<0>(lds, 0, aRowBase, ck0, ck1, a);
    STG(t1, 1);
    SYNC_MFMA(0)
    rd_a<1>(lds, 0, aRowBase, ck0, ck1, a);
    STG(t2, 2); STG(t2, 3); STG(t2, 0);
    SYNC_MFMA(1)
    rd_b(lds, 32768, bRowBase, ck0, ck1, b);
    rd_a<0>(lds, 32768, aRowBase, ck0, ck1, a);
    STG(t2, 1);
    SYNC_MFMA(0)
    rd_a<1>(lds, 32768, aRowBase, ck0, ck1, a);
    STG(t3, 2); STG(t3, 3); STG(t3, 0);
    SYNC_MFMA(1)
  }
}

#define ACC_ZERO()                                                             \
  ffrag acc[8][4];                                                             \
  _Pragma("unroll") for (int m = 0; m < 8; ++m)                                \
  _Pragma("unroll") for (int n = 0; n < 4; ++n) acc[m][n] = (ffrag)(0.0f);

// Epilogue mapping for acc[i][j]: qa=i>>2, m=i&3, qb=j>>1, n=j&1.
// row = brow + qa*128 + wr*64 + m*16 + (lane>>4)*4 + r
// col = bcol + qb*128 + wc*32 + n*16 + (lane&15)

// ---------------- kernel 1: qkv projection (V written transposed) ----------
__global__ __launch_bounds__(512, 2) void qkv_gemm256(
    const __bf16* __restrict__ Abf, const __bf16* __restrict__ Wbf,
    const float* __restrict__ bias,
    __bf16* __restrict__ Q, __bf16* __restrict__ Ko, __bf16* __restrict__ Vt) {
  __shared__ __bf16 lds[65536];
  ACC_ZERO();
  int bid = (int)blockIdx.x;
  bid = (bid & 7) * 96 + (bid >> 3);          // XCD swizzle (768 % 8 == 0, bijective)
  const int brow = (bid / 12) * 256;
  const int bcol = (bid % 12) * 256;
  gemm256_mainloop(Abf + (size_t)brow * 1024, Wbf + (size_t)bcol * 1024,
                   1024, 1024, 1024, lds, acc);
  const int lane = threadIdx.x & 63, wid = threadIdx.x >> 6;
  const int wr = wid >> 2, wc = wid & 3;
  const int region = bcol >> 10;              // 0=Q,1=K,2=V (tile within one region)
  if (region < 2) {
    __bf16* dst = region == 0 ? Q : Ko;
    const float scale = region == 0 ? 0.03125f : 1.0f;  // fold 1/sqrt(1024) into Q
#pragma unroll
    for (int j = 0; j < 4; ++j) {
      const int qb = j >> 1, n = j & 1;
      const int col = bcol + qb * 128 + wc * 32 + n * 16 + (lane & 15);
      const int o = col & 1023;
      const float bv = bias[col];
#pragma unroll
      for (int i = 0; i < 8; ++i) {
        const int qa = i >> 2, m = i & 3;
#pragma unroll
        for (int r = 0; r < 4; ++r) {
          const int mg = brow + qa * 128 + wr * 64 + m * 16 + (lane >> 4) * 4 + r;
          dst[(size_t)mg * 1024 + o] = (__bf16)((acc[i][j][r] + bv) * scale);
        }
      }
    }
  } else {
    // V: write transposed Vt[b][d][n]; 4 consecutive n-rows pack into one 8B store
#pragma unroll
    for (int j = 0; j < 4; ++j) {
      const int qb = j >> 1, n = j & 1;
      const int col = bcol + qb * 128 + wc * 32 + n * 16 + (lane & 15);
      const int o = col & 1023;                // d index
      const float bv = bias[col];
#pragma unroll
      for (int i = 0; i < 8; ++i) {
        const int qa = i >> 2, m = i & 3;
        const int mg0 = brow + qa * 128 + wr * 64 + m * 16 + (lane >> 4) * 4;
        const int b = mg0 >> 11, nr = mg0 & 2047;
        bf16x4 v;
#pragma unroll
        for (int r = 0; r < 4; ++r) v[r] = (__bf16)(acc[i][j][r] + bv);
        *(bf16x4*)&Vt[(size_t)b * 2097152 + (size_t)o * 2048 + nr] = v;
      }
    }
  }
}

// ---------------- kernel 2: scores S = Q K^T (Q pre-scaled), bf16 out ------
__global__ __launch_bounds__(512, 2) void scores_gemm256(const __bf16* __restrict__ Q,
                                                         const __bf16* __restrict__ Kb,
                                                         __bf16* __restrict__ S) {
  __shared__ __bf16 lds[65536];
  ACC_ZERO();
  int bid = (int)blockIdx.x;                  // 512 blocks: XCD swizzle, batch-per-XCD
  const int wg = (bid & 7) * 64 + (bid >> 3);
  const int brow = (wg & 7) * 256, bcol = ((wg >> 3) & 7) * 256, z = wg >> 6;
  gemm256_mainloop(Q + (size_t)z * 2048 * 1024 + (size_t)brow * 1024,
                   Kb + (size_t)z * 2048 * 1024 + (size_t)bcol * 1024,
                   1024, 1024, 1024, lds, acc);
  const int lane = threadIdx.x & 63, wid = threadIdx.x >> 6;
  const int wr = wid >> 2, wc = wid & 3;
#pragma unroll
  for (int j = 0; j < 4; ++j) {
    const int qb = j >> 1, n = j & 1;
    const int o = bcol + qb * 128 + wc * 32 + n * 16 + (lane & 15);
#pragma unroll
    for (int i = 0; i < 8; ++i) {
      const int qa = i >> 2, m = i & 3;
#pragma unroll
      for (int r = 0; r < 4; ++r) {
        const int mg = brow + qa * 128 + wr * 64 + m * 16 + (lane >> 4) * 4 + r;
        S[((size_t)(z * 2048 + mg)) * 2048 + o] = (__bf16)acc[i][j][r];
      }
    }
  }
}

// ---------------- kernel 3: in-place bf16 row softmax ----------------------
__global__ __launch_bounds__(256) void softmax_bf16(__bf16* S) {
  const int row = blockIdx.x;
  __bf16* s = S + (size_t)row * 2048;
  const int t = threadIdx.x;
  bf16x8 v = *(const bf16x8*)&s[t * 8];
  float f[8];
#pragma unroll
  for (int j = 0; j < 8; ++j) f[j] = (float)v[j];
  float m = fmaxf(fmaxf(fmaxf(f[0], f[1]), fmaxf(f[2], f[3])),
                  fmaxf(fmaxf(f[4], f[5]), fmaxf(f[6], f[7])));
#pragma unroll
  for (int off = 32; off; off >>= 1) m = fmaxf(m, __shfl_xor(m, off, 64));
  __shared__ float redm[4];
  if ((t & 63) == 0) redm[t >> 6] = m;
  __syncthreads();
  m = fmaxf(fmaxf(redm[0], redm[1]), fmaxf(redm[2], redm[3]));
  float e[8], sum = 0.f;
#pragma unroll
  for (int j = 0; j < 8; ++j) { e[j] = __expf(f[j] - m); sum += e[j]; }
#pragma unroll
  for (int off = 32; off; off >>= 1) sum += __shfl_xor(sum, off, 64);
  __shared__ float reds[4];
  if ((t & 63) == 0) reds[t >> 6] = sum;
  __syncthreads();
  float inv = 1.0f / (((reds[0] + reds[1]) + (reds[2] + reds[3])));
  bf16x8 o;
#pragma unroll
  for (int j = 0; j < 8; ++j) o[j] = (__bf16)(e[j] * inv);
  *(bf16x8*)&s[t * 8] = o;
}

// ---------------- kernel 4: out = P @ V  (via Vt, B^T form) ----------------
__global__ __launch_bounds__(512, 2) void pv_gemm256(const __bf16* __restrict__ P,
                                                     const __bf16* __restrict__ Vt,
                                                     float* __restrict__ O) {
  __shared__ __bf16 lds[65536];
  ACC_ZERO();
  int bid = (int)blockIdx.x;                  // 256 blocks: XCD swizzle, batch-per-XCD
  const int wg = (bid & 7) * 32 + (bid >> 3);
  const int brow = (wg & 7) * 256, bcol = ((wg >> 3) & 3) * 256, z = wg >> 5;
  gemm256_mainloop(P + (size_t)(z * 2048 + brow) * 2048,
                   Vt + (size_t)z * 1024 * 2048 + (size_t)bcol * 2048,
                   2048, 2048, 2048, lds, acc);
  const int lane = threadIdx.x & 63, wid = threadIdx.x >> 6;
  const int wr = wid >> 2, wc = wid & 3;
#pragma unroll
  for (int j = 0; j < 4; ++j) {
    const int qb = j >> 1, n = j & 1;
    const int o = bcol + qb * 128 + wc * 32 + n * 16 + (lane & 15);
#pragma unroll
    for (int i = 0; i < 8; ++i) {
      const int qa = i >> 2, m = i & 3;
#pragma unroll
      for (int r = 0; r < 4; ++r) {
        const int mg = brow + qa * 128 + wr * 64 + m * 16 + (lane >> 4) * 4 + r;
        O[((size_t)(z * 2048 + mg)) * 1024 + o] = acc[i][j][r];
      }
    }
  }
}

extern "C" void kernel_launch(void* const* d_in, const int* in_sizes, int n_in,
                              void* d_out, int out_size, void* d_ws, size_t ws_size,
                              hipStream_t stream) {
  (void)in_sizes; (void)n_in; (void)out_size; (void)ws_size;
  const float* x    = (const float*)d_in[0];
  const float* W    = (const float*)d_in[1];
  const float* bias = (const float*)d_in[2];
  float* out = (float*)d_out;
  char* ws = (char*)d_ws;
  const size_t MB = 1u << 20;
  __bf16* x_bf = (__bf16*)(ws + 0);
  __bf16* W_bf = (__bf16*)(ws + 32 * MB);
  __bf16* Qb   = (__bf16*)(ws + 38 * MB);
  __bf16* Kb   = (__bf16*)(ws + 70 * MB);
  __bf16* S    = (__bf16*)(ws + 102 * MB);   // bf16 scores, softmax in-place -> P
  __bf16* Vt   = (__bf16*)(ws + 166 * MB);   // V^T, written by qkv epilogue

  cvt_f32_bf16<<<2048, 256, 0, stream>>>(x, x_bf, 16777216 / 4);
  cvt_f32_bf16<<<1024, 256, 0, stream>>>(W, W_bf, 3145728 / 4);
  qkv_gemm256<<<768, 512, 0, stream>>>(x_bf, W_bf, bias, Qb, Kb, Vt);
  scores_gemm256<<<512, 512, 0, stream>>>(Qb, Kb, S);
  softmax_bf16<<<16384, 256, 0, stream>>>(S);
  pv_gemm256<<<256, 512, 0, stream>>>(S, Vt, out);
}

// Round 8
// 285.832 us; speedup vs baseline: 1.2196x; 1.0754x over previous
//
#include <hip/hip_runtime.h>

// AttentionHead: B=8, N=2048, D=1024
// qkv = x @ W^T + b ; q,k,v split ; S = qk^T/32 ; P = softmax(S) ; out = P v
// Pipeline: cvt -> qkv_gemm256 (writes Q, K, V^T) -> scores_gemm256 (bf16 S)
//           -> softmax_bf16 (in-place, wave-per-row) -> pv_gemm256
// GEMMs: 256x256 4-phase schedule, region-staggered staging (round-5 proof),
//   RELAXED FENCES (round-8): no blanket lgkmcnt(0); compiler emits fine-grained
//   per-MFMA lgkmcnt so read latency hides under the MFMA cluster. Pins kept:
//   sched_barrier(0) after vmcnt (vmcnt->barrier adjacency) and at phase end
//   (stops cross-phase read hoisting; preserves the staging-confirmation order
//   vmcnt+barrier1(p) < barrier2(p) < reads(p+1)).
// Workspace layout (peak 198 MiB):
//   [0,32MB)    x_bf          [32,38MB)  W_bf
//   [38,70MB)   Q bf16        [70,102MB) K bf16
//   [102,166MB) S bf16 rows stride 2048 (softmax in-place -> P)
//   [166,198MB) Vt bf16 [b][d][n]

#define AS1 __attribute__((address_space(1)))
#define AS3 __attribute__((address_space(3)))

typedef __bf16 bfrag  __attribute__((ext_vector_type(8)));
typedef float  ffrag  __attribute__((ext_vector_type(4)));
typedef __bf16 bf16x4 __attribute__((ext_vector_type(4)));
typedef __bf16 bf16x8 __attribute__((ext_vector_type(8)));

// ---------------- f32 -> bf16 convert, x4 vectorized ----------------
__global__ __launch_bounds__(256) void cvt_f32_bf16(const float* __restrict__ in,
                                                    __bf16* __restrict__ out, int n4) {
  int i = blockIdx.x * blockDim.x + threadIdx.x;
  int stride = gridDim.x * blockDim.x;
  for (; i < n4; i += stride) {
    float4 v = ((const float4*)in)[i];
    bf16x4 o;
    o[0] = (__bf16)v.x; o[1] = (__bf16)v.y; o[2] = (__bf16)v.z; o[3] = (__bf16)v.w;
    ((bf16x4*)out)[i] = o;
  }
}

// =================== 256x256 4-phase GEMM mainloop ===================
__device__ __forceinline__ void stage_half(
    const __bf16* __restrict__ Atile, const __bf16* __restrict__ Btile,
    int lda, int ldb, int nT, __bf16* lds, int tid, int t, int h) {
  const int te = (t < nT) ? t : (t - 2);   // same parity -> same buffer, same data
  const int kt = te * 64;
  const __bf16* src = (h < 2) ? Atile : Btile;
  const int ld = (h < 2) ? lda : ldb;
  const int row0 = (h & 1) * 128;
  __bf16* dst = lds + (te & 1) * 32768 + h * 8192;
#pragma unroll
  for (int l = 0; l < 2; ++l) {
    const int y = l * 4096 + tid * 8;                  // linear LDS dest (uniform base + lane*16B)
    const int r = y >> 6;                              // row within half (0..127)
    const int c = ((tid & 7) * 8) ^ ((r & 7) << 3);    // inverse-swizzled source col
    __builtin_amdgcn_global_load_lds((AS1 void*)(src + (size_t)(row0 + r) * ld + kt + c),
                                     (AS3 void*)(dst + y), 16, 0, 0);
  }
}

__device__ __forceinline__ void rd_b(const __bf16* lds, int bufoff, int bRowBase,
                                     int ck0, int ck1, bfrag b[4][2]) {
#pragma unroll
  for (int j = 0; j < 4; ++j) {
    const int off = bufoff + bRowBase + (j >> 1) * 8192 + (j & 1) * 1024;
    b[j][0] = *(const bfrag*)&lds[off + ck0];
    b[j][1] = *(const bfrag*)&lds[off + ck1];
  }
}

template <int QA>
__device__ __forceinline__ void rd_a(const __bf16* lds, int bufoff, int aRowBase,
                                     int ck0, int ck1, bfrag a[4][2]) {
#pragma unroll
  for (int m = 0; m < 4; ++m) {
    const int off = bufoff + aRowBase + QA * 8192 + m * 1024;
    a[m][0] = *(const bfrag*)&lds[off + ck0];
    a[m][1] = *(const bfrag*)&lds[off + ck1];
  }
}

template <int QA>
__device__ __forceinline__ void mfma_q(const bfrag a[4][2], const bfrag b[4][2],
                                       ffrag acc[8][4]) {
#pragma unroll
  for (int m = 0; m < 4; ++m)
#pragma unroll
    for (int j = 0; j < 4; ++j)
#pragma unroll
      for (int ks = 0; ks < 2; ++ks)
        acc[QA * 4 + m][j] = __builtin_amdgcn_mfma_f32_16x16x32_bf16(
            a[m][ks], b[j][ks], acc[QA * 4 + m][j], 0, 0, 0);
}

// Relaxed-fence phase sync: vmcnt keeps the staging pipeline counted; no
// lgkmcnt(0) — the compiler inserts fine-grained lgkmcnt per MFMA operand.
#define SYNC_MFMA(QA)                                                          \
    asm volatile("s_waitcnt vmcnt(8)" ::: "memory");                           \
    __builtin_amdgcn_sched_barrier(0);                                         \
    __builtin_amdgcn_s_barrier();                                              \
    __builtin_amdgcn_s_setprio(1);                                             \
    mfma_q<QA>(a, b, acc);                                                     \
    __builtin_amdgcn_s_setprio(0);                                             \
    __builtin_amdgcn_s_barrier();                                              \
    __builtin_amdgcn_sched_barrier(0);

#define STG(T, H) stage_half(Atile, Btile, lda, ldb, nT, lds, tid, (T), (H))

__device__ __forceinline__ void gemm256_mainloop(
    const __bf16* __restrict__ Atile, const __bf16* __restrict__ Btile,
    int lda, int ldb, int K, __bf16* lds, ffrag acc[8][4]) {
  const int tid  = threadIdx.x;
  const int lane = tid & 63;
  const int wid  = tid >> 6;
  const int wr   = wid >> 2, wc = wid & 3;
  const int fr   = lane & 15;
  const int fk   = (lane >> 4) * 8;
  const int swz  = (fr & 7) << 3;
  const int ck0  = fk ^ swz;            // ks=0 frag col (swizzled)
  const int ck1  = (32 + fk) ^ swz;     // ks=1
  const int aRowBase = (wr * 64 + fr) * 64;
  const int bRowBase = 16384 + (wc * 32 + fr) * 64;
  const int nT = K >> 6;

  // prologue: t0 {B0,B1,A0,A1}; t1 {B0,B1,A0}. vmcnt(8) -> t0.{B0,B1,A0} done.
  STG(0, 2); STG(0, 3); STG(0, 0); STG(0, 1);
  STG(1, 2); STG(1, 3); STG(1, 0);
  asm volatile("s_waitcnt vmcnt(8)" ::: "memory");
  __builtin_amdgcn_s_barrier();
  __builtin_amdgcn_sched_barrier(0);

  const int nIter = nT >> 1;
#pragma unroll 1
  for (int i = 0; i < nIter; ++i) {
    const int t1 = 2 * i + 1, t2 = 2 * i + 2, t3 = 2 * i + 3;
    bfrag a[4][2], b[4][2];
    // P1: buf0 qa=0 (reads B0,B1,A0 of tile 2i); stage A1(2i+1)
    rd_b(lds, 0, bRowBase, ck0, ck1, b);
    rd_a<0>(lds, 0, aRowBase, ck0, ck1, a);
    STG(t1, 1);
    SYNC_MFMA(0)
    // P2: buf0 qa=1 (reads A1 of tile 2i; b reused); stage {B0,B1,A0}(2i+2)
    rd_a<1>(lds, 0, aRowBase, ck0, ck1, a);
    STG(t2, 2); STG(t2, 3); STG(t2, 0);
    SYNC_MFMA(1)
    // P3: buf1 qa=0 (reads B0,B1,A0 of tile 2i+1); stage A1(2i+2)
    rd_b(lds, 32768, bRowBase, ck0, ck1, b);
    rd_a<0>(lds, 32768, aRowBase, ck0, ck1, a);
    STG(t2, 1);
    SYNC_MFMA(0)
    // P4: buf1 qa=1 (reads A1 of tile 2i+1); stage {B0,B1,A0}(2i+3)
    rd_a<1>(lds, 32768, aRowBase, ck0, ck1, a);
    STG(t3, 2); STG(t3, 3); STG(t3, 0);
    SYNC_MFMA(1)
  }
}

#define ACC_ZERO()                                                             \
  ffrag acc[8][4];                                                             \
  _Pragma("unroll") for (int m = 0; m < 8; ++m)                                \
  _Pragma("unroll") for (int n = 0; n < 4; ++n) acc[m][n] = (ffrag)(0.0f);

// Epilogue mapping for acc[i][j]: qa=i>>2, m=i&3, qb=j>>1, n=j&1.
// row = brow + qa*128 + wr*64 + m*16 + (lane>>4)*4 + r
// col = bcol + qb*128 + wc*32 + n*16 + (lane&15)

// ---------------- kernel 1: qkv projection (V written transposed) ----------
__global__ __launch_bounds__(512, 2) void qkv_gemm256(
    const __bf16* __restrict__ Abf, const __bf16* __restrict__ Wbf,
    const float* __restrict__ bias,
    __bf16* __restrict__ Q, __bf16* __restrict__ Ko, __bf16* __restrict__ Vt) {
  __shared__ __bf16 lds[65536];
  ACC_ZERO();
  int bid = (int)blockIdx.x;
  bid = (bid & 7) * 96 + (bid >> 3);          // XCD swizzle (768 % 8 == 0, bijective)
  const int brow = (bid / 12) * 256;
  const int bcol = (bid % 12) * 256;
  gemm256_mainloop(Abf + (size_t)brow * 1024, Wbf + (size_t)bcol * 1024,
                   1024, 1024, 1024, lds, acc);
  const int lane = threadIdx.x & 63, wid = threadIdx.x >> 6;
  const int wr = wid >> 2, wc = wid & 3;
  const int region = bcol >> 10;              // 0=Q,1=K,2=V (tile within one region)
  if (region < 2) {
    __bf16* dst = region == 0 ? Q : Ko;
    const float scale = region == 0 ? 0.03125f : 1.0f;  // fold 1/sqrt(1024) into Q
#pragma unroll
    for (int j = 0; j < 4; ++j) {
      const int qb = j >> 1, n = j & 1;
      const int col = bcol + qb * 128 + wc * 32 + n * 16 + (lane & 15);
      const int o = col & 1023;
      const float bv = bias[col];
#pragma unroll
      for (int i = 0; i < 8; ++i) {
        const int qa = i >> 2, m = i & 3;
#pragma unroll
        for (int r = 0; r < 4; ++r) {
          const int mg = brow + qa * 128 + wr * 64 + m * 16 + (lane >> 4) * 4 + r;
          dst[(size_t)mg * 1024 + o] = (__bf16)((acc[i][j][r] + bv) * scale);
        }
      }
    }
  } else {
    // V: write transposed Vt[b][d][n]; 4 consecutive n-rows pack into one 8B store
#pragma unroll
    for (int j = 0; j < 4; ++j) {
      const int qb = j >> 1, n = j & 1;
      const int col = bcol + qb * 128 + wc * 32 + n * 16 + (lane & 15);
      const int o = col & 1023;                // d index
      const float bv = bias[col];
#pragma unroll
      for (int i = 0; i < 8; ++i) {
        const int qa = i >> 2, m = i & 3;
        const int mg0 = brow + qa * 128 + wr * 64 + m * 16 + (lane >> 4) * 4;
        const int b = mg0 >> 11, nr = mg0 & 2047;
        bf16x4 v;
#pragma unroll
        for (int r = 0; r < 4; ++r) v[r] = (__bf16)(acc[i][j][r] + bv);
        *(bf16x4*)&Vt[(size_t)b * 2097152 + (size_t)o * 2048 + nr] = v;
      }
    }
  }
}

// ---------------- kernel 2: scores S = Q K^T (Q pre-scaled), bf16 out ------
__global__ __launch_bounds__(512, 2) void scores_gemm256(const __bf16* __restrict__ Q,
                                                         const __bf16* __restrict__ Kb,
                                                         __bf16* __restrict__ S) {
  __shared__ __bf16 lds[65536];
  ACC_ZERO();
  int bid = (int)blockIdx.x;                  // 512 blocks: XCD swizzle, batch-per-XCD
  const int wg = (bid & 7) * 64 + (bid >> 3);
  const int brow = (wg & 7) * 256, bcol = ((wg >> 3) & 7) * 256, z = wg >> 6;
  gemm256_mainloop(Q + (size_t)z * 2048 * 1024 + (size_t)brow * 1024,
                   Kb + (size_t)z * 2048 * 1024 + (size_t)bcol * 1024,
                   1024, 1024, 1024, lds, acc);
  const int lane = threadIdx.x & 63, wid = threadIdx.x >> 6;
  const int wr = wid >> 2, wc = wid & 3;
#pragma unroll
  for (int j = 0; j < 4; ++j) {
    const int qb = j >> 1, n = j & 1;
    const int o = bcol + qb * 128 + wc * 32 + n * 16 + (lane & 15);
#pragma unroll
    for (int i = 0; i < 8; ++i) {
      const int qa = i >> 2, m = i & 3;
#pragma unroll
      for (int r = 0; r < 4; ++r) {
        const int mg = brow + qa * 128 + wr * 64 + m * 16 + (lane >> 4) * 4 + r;
        S[((size_t)(z * 2048 + mg)) * 2048 + o] = (__bf16)acc[i][j][r];
      }
    }
  }
}

// ---------------- kernel 3: in-place bf16 row softmax (wave per row) -------
__global__ __launch_bounds__(256) void softmax_bf16(__bf16* S) {
  const int row = blockIdx.x * 4 + (threadIdx.x >> 6);
  const int lane = threadIdx.x & 63;
  __bf16* s = S + (size_t)row * 2048 + lane * 8;
  float f[32];
#pragma unroll
  for (int c = 0; c < 4; ++c) {
    bf16x8 v = *(const bf16x8*)&s[c * 512];
#pragma unroll
    for (int j = 0; j < 8; ++j) f[c * 8 + j] = (float)v[j];
  }
  float m = f[0];
#pragma unroll
  for (int j = 1; j < 32; ++j) m = fmaxf(m, f[j]);
#pragma unroll
  for (int off = 32; off; off >>= 1) m = fmaxf(m, __shfl_xor(m, off, 64));
  float sum = 0.f;
#pragma unroll
  for (int j = 0; j < 32; ++j) { f[j] = __expf(f[j] - m); sum += f[j]; }
#pragma unroll
  for (int off = 32; off; off >>= 1) sum += __shfl_xor(sum, off, 64);
  const float inv = 1.0f / sum;
#pragma unroll
  for (int c = 0; c < 4; ++c) {
    bf16x8 o;
#pragma unroll
    for (int j = 0; j < 8; ++j) o[j] = (__bf16)(f[c * 8 + j] * inv);
    *(bf16x8*)&s[c * 512] = o;
  }
}

// ---------------- kernel 4: out = P @ V  (via Vt, B^T form) ----------------
__global__ __launch_bounds__(512, 2) void pv_gemm256(const __bf16* __restrict__ P,
                                                     const __bf16* __restrict__ Vt,
                                                     float* __restrict__ O) {
  __shared__ __bf16 lds[65536];
  ACC_ZERO();
  int bid = (int)blockIdx.x;                  // 256 blocks: XCD swizzle, batch-per-XCD
  const int wg = (bid & 7) * 32 + (bid >> 3);
  const int brow = (wg & 7) * 256, bcol = ((wg >> 3) & 3) * 256, z = wg >> 5;
  gemm256_mainloop(P + (size_t)(z * 2048 + brow) * 2048,
                   Vt + (size_t)z * 1024 * 2048 + (size_t)bcol * 2048,
                   2048, 2048, 2048, lds, acc);
  const int lane = threadIdx.x & 63, wid = threadIdx.x >> 6;
  const int wr = wid >> 2, wc = wid & 3;
#pragma unroll
  for (int j = 0; j < 4; ++j) {
    const int qb = j >> 1, n = j & 1;
    const int o = bcol + qb * 128 + wc * 32 + n * 16 + (lane & 15);
#pragma unroll
    for (int i = 0; i < 8; ++i) {
      const int qa = i >> 2, m = i & 3;
#pragma unroll
      for (int r = 0; r < 4; ++r) {
        const int mg = brow + qa * 128 + wr * 64 + m * 16 + (lane >> 4) * 4 + r;
        O[((size_t)(z * 2048 + mg)) * 1024 + o] = acc[i][j][r];
      }
    }
  }
}

extern "C" void kernel_launch(void* const* d_in, const int* in_sizes, int n_in,
                              void* d_out, int out_size, void* d_ws, size_t ws_size,
                              hipStream_t stream) {
  (void)in_sizes; (void)n_in; (void)out_size; (void)ws_size;
  const float* x    = (const float*)d_in[0];
  const float* W    = (const float*)d_in[1];
  const float* bias = (const float*)d_in[2];
  float* out = (float*)d_out;
  char* ws = (char*)d_ws;
  const size_t MB = 1u << 20;
  __bf16* x_bf = (__bf16*)(ws + 0);
  __bf16* W_bf = (__bf16*)(ws + 32 * MB);
  __bf16* Qb   = (__bf16*)(ws + 38 * MB);
  __bf16* Kb   = (__bf16*)(ws + 70 * MB);
  __bf16* S    = (__bf16*)(ws + 102 * MB);   // bf16 scores, softmax in-place -> P
  __bf16* Vt   = (__bf16*)(ws + 166 * MB);   // V^T, written by qkv epilogue

  cvt_f32_bf16<<<2048, 256, 0, stream>>>(x, x_bf, 16777216 / 4);
  cvt_f32_bf16<<<1024, 256, 0, stream>>>(W, W_bf, 3145728 / 4);
  qkv_gemm256<<<768, 512, 0, stream>>>(x_bf, W_bf, bias, Qb, Kb, Vt);
  scores_gemm256<<<512, 512, 0, stream>>>(Qb, Kb, S);
  softmax_bf16<<<4096, 256, 0, stream>>>(S);
  pv_gemm256<<<256, 512, 0, stream>>>(S, Vt, out);
}

// Round 9
// 278.373 us; speedup vs baseline: 1.2522x; 1.0268x over previous
//
#include <hip/hip_runtime.h>

// AttentionHead: B=8, N=2048, D=1024
// qkv = x @ W^T + b ; q,k,v split ; S = qk^T/32 ; P = softmax(S) ; out = P v
// Pipeline: cvt -> qkv_gemm256 (writes Q, K, V^T) -> scores_gemm256 (bf16 S)
//           -> softmax_bf16 (in-place, wave-per-row) -> pv_gemm256
// GEMMs: faithful m201 8-phase schedule (round-9): per 2 K-tiles, 8 phases of
//   {ds_read subtile (12/4/8/0 x b128) | stage 1 half (2 gload_lds) |
//    [vmcnt(6) @P4,P8] | barrier | lgkmcnt(0) | setprio(1) 16 MFMA setprio(0) |
//    barrier}. Zigzag quadrants (00,01,11,10); a0/b0/b1/a1 held in regs ->
//   24 ds_read_b128 per wave per K-tile (minimum). Stage slot p targets the
//   region freed in phase p-1 (race-free; full trace in session notes):
//   P1:A1(t1) P2:A0(t2) P3:B0(t2) P4:B1(t2) P5:A1(t2) P6:A0(t3) P7:B0(t3)
//   P8:B1(t3) nextP1:A1(t3). vmcnt(6)=3 halves in flight, never drains (T4).
// Workspace layout (peak 198 MiB):
//   [0,32MB)    x_bf          [32,38MB)  W_bf
//   [38,70MB)   Q bf16        [70,102MB) K bf16
//   [102,166MB) S bf16 rows stride 2048 (softmax in-place -> P)
//   [166,198MB) Vt bf16 [b][d][n]

#define AS1 __attribute__((address_space(1)))
#define AS3 __attribute__((address_space(3)))

typedef __bf16 bfrag  __attribute__((ext_vector_type(8)));
typedef float  ffrag  __attribute__((ext_vector_type(4)));
typedef __bf16 bf16x4 __attribute__((ext_vector_type(4)));
typedef __bf16 bf16x8 __attribute__((ext_vector_type(8)));

// ---------------- f32 -> bf16 convert, x4 vectorized ----------------
__global__ __launch_bounds__(256) void cvt_f32_bf16(const float* __restrict__ in,
                                                    __bf16* __restrict__ out, int n4) {
  int i = blockIdx.x * blockDim.x + threadIdx.x;
  int stride = gridDim.x * blockDim.x;
  for (; i < n4; i += stride) {
    float4 v = ((const float4*)in)[i];
    bf16x4 o;
    o[0] = (__bf16)v.x; o[1] = (__bf16)v.y; o[2] = (__bf16)v.z; o[3] = (__bf16)v.w;
    ((bf16x4*)out)[i] = o;
  }
}

// =================== 256x256 8-phase GEMM mainloop (m201 port) ===============
// C[m][o] = sum_k A[m][k] * B[o][k]  (both K-major, B^T form)
// 512 threads = 8 waves (wr = wid>>2 in {0,1}, wc = wid&3 in {0..3}).
// LDS 128 KiB: buf{0,1} x (A[256][64] | B[256][64]) bf16, tile t -> buf t&1.
// Half-regions (8 KiB elems each): h0=A rows 0-127, h1=A rows 128-255,
// h2=B rows 0-127, h3=B rows 128-255, elem offset h*8192 in the buffer.
// Wave quadrants span both halves: A row = qa*128 + wr*64 + m*16 + fr,
// B row = qb*128 + wc*32 + n*16 + fr  -> each region's LDS reads occur in
// exactly one phase (regs held across phases), enabling the 1-half/phase
// stagger. Swizzle: LDS[r][c] = G[r][c ^ ((r&7)<<3)], inverse-applied on the
// global source col; gload_lds dest stays linear.

__device__ __forceinline__ void stage_half(
    const __bf16* __restrict__ Atile, const __bf16* __restrict__ Btile,
    int lda, int ldb, __bf16* lds, int tid, int te, int h) {
  const int kt = te * 64;
  const __bf16* src = (h < 2) ? Atile : Btile;
  const int ld = (h < 2) ? lda : ldb;
  const int row0 = (h & 1) * 128;
  __bf16* dst = lds + (te & 1) * 32768 + h * 8192;
#pragma unroll
  for (int l = 0; l < 2; ++l) {
    const int y = l * 4096 + tid * 8;                  // linear LDS dest (uniform base + lane*16B)
    const int r = y >> 6;                              // row within half (0..127)
    const int c = ((tid & 7) * 8) ^ ((r & 7) << 3);    // inverse-swizzled source col
    __builtin_amdgcn_global_load_lds((AS1 void*)(src + (size_t)(row0 + r) * ld + kt + c),
                                     (AS3 void*)(dst + y), 16, 0, 0);
  }
}

template <int QA>
__device__ __forceinline__ void rd_a(const __bf16* lds, int bufoff, int aRowBase,
                                     int ck0, int ck1, bfrag a[4][2]) {
#pragma unroll
  for (int m = 0; m < 4; ++m) {
    const int off = bufoff + aRowBase + QA * 8192 + m * 1024;
    a[m][0] = *(const bfrag*)&lds[off + ck0];
    a[m][1] = *(const bfrag*)&lds[off + ck1];
  }
}

template <int QB>
__device__ __forceinline__ void rd_bq(const __bf16* lds, int bufoff, int bRowBase,
                                      int ck0, int ck1, bfrag b[2][2]) {
#pragma unroll
  for (int n = 0; n < 2; ++n) {
    const int off = bufoff + bRowBase + QB * 8192 + n * 1024;
    b[n][0] = *(const bfrag*)&lds[off + ck0];
    b[n][1] = *(const bfrag*)&lds[off + ck1];
  }
}

// One phase tail: [vmcnt(6)] barrier; lgkmcnt(0); 16 MFMA (quadrant QA,QB); barrier.
#define PH(QA, QB, BREG, DOVM)                                                 \
  {                                                                            \
    if (DOVM) asm volatile("s_waitcnt vmcnt(6)" ::: "memory");                 \
    __builtin_amdgcn_s_barrier();                                              \
    asm volatile("s_waitcnt lgkmcnt(0)" ::: "memory");                         \
    __builtin_amdgcn_s_setprio(1);                                             \
    _Pragma("unroll") for (int m_ = 0; m_ < 4; ++m_)                           \
    _Pragma("unroll") for (int n_ = 0; n_ < 2; ++n_)                           \
    _Pragma("unroll") for (int ks_ = 0; ks_ < 2; ++ks_)                        \
      acc[(QA) * 4 + m_][(QB) * 2 + n_] =                                      \
          __builtin_amdgcn_mfma_f32_16x16x32_bf16(                             \
              a[m_][ks_], BREG[n_][ks_], acc[(QA) * 4 + m_][(QB) * 2 + n_],    \
              0, 0, 0);                                                        \
    __builtin_amdgcn_s_setprio(0);                                             \
    __builtin_amdgcn_s_barrier();                                              \
    __builtin_amdgcn_sched_barrier(0);                                         \
  }

#define STG(TE, H) stage_half(Atile, Btile, lda, ldb, lds, tid, (TE), (H))

__device__ __forceinline__ void gemm256_mainloop(
    const __bf16* __restrict__ Atile, const __bf16* __restrict__ Btile,
    int lda, int ldb, int K, __bf16* lds, ffrag acc[8][4]) {
  const int tid  = threadIdx.x;
  const int lane = tid & 63;
  const int wid  = tid >> 6;
  const int wr   = wid >> 2, wc = wid & 3;
  const int fr   = lane & 15;
  const int fk   = (lane >> 4) * 8;
  const int swz  = (fr & 7) << 3;
  const int ck0  = fk ^ swz;            // ks=0 frag col (swizzled)
  const int ck1  = (32 + fk) ^ swz;     // ks=1
  const int aRowBase = (wr * 64 + fr) * 64;
  const int bRowBase = 16384 + (wc * 32 + fr) * 64;
  const int nT = K >> 6;

  // prologue (steady-state-matching order): A0,B0,B1,A1 of T0; A0,B0,B1 of T1.
  // vmcnt(6) -> all of T0 confirmed; 3 halves (T1's) in flight.
  STG(0, 0); STG(0, 2); STG(0, 3); STG(0, 1);
  STG(1, 0); STG(1, 2); STG(1, 3);
  asm volatile("s_waitcnt vmcnt(6)" ::: "memory");
  __builtin_amdgcn_s_barrier();

  const int nIter = nT >> 1;
#pragma unroll 1
  for (int i = 0; i < nIter; ++i) {
    const int t1  = 2 * i + 1;
    const int t2e = (2 * i + 2 < nT) ? (2 * i + 2) : (2 * i);      // tail wrap,
    const int t3e = (2 * i + 3 < nT) ? (2 * i + 3) : (2 * i + 1);  // same parity
    bfrag a[4][2], b0f[2][2], b1f[2][2];
    // P1 (qa0,qb0): read a0 (8) + b0 (4); stage A1(t1)
    rd_a<0>(lds, 0, aRowBase, ck0, ck1, a);
    rd_bq<0>(lds, 0, bRowBase, ck0, ck1, b0f);
    STG(t1, 1);
    PH(0, 0, b0f, false)
    // P2 (qa0,qb1): read b1 (4); a held; stage A0(t2)
    rd_bq<1>(lds, 0, bRowBase, ck0, ck1, b1f);
    STG(t2e, 0);
    PH(0, 1, b1f, false)
    // P3 (qa1,qb1): read a1 (8); b1 held; stage B0(t2)
    rd_a<1>(lds, 0, aRowBase, ck0, ck1, a);
    STG(t2e, 2);
    PH(1, 1, b1f, false)
    // P4 (qa1,qb0): no reads (a1,b0 held); stage B1(t2); vmcnt(6)
    STG(t2e, 3);
    PH(1, 0, b0f, true)
    // P5 (qa0,qb0) on buf1: read a0+b0; stage A1(t2)
    rd_a<0>(lds, 32768, aRowBase, ck0, ck1, a);
    rd_bq<0>(lds, 32768, bRowBase, ck0, ck1, b0f);
    STG(t2e, 1);
    PH(0, 0, b0f, false)
    // P6 (qa0,qb1): read b1; stage A0(t3)
    rd_bq<1>(lds, 32768, bRowBase, ck0, ck1, b1f);
    STG(t3e, 0);
    PH(0, 1, b1f, false)
    // P7 (qa1,qb1): read a1; stage B0(t3)
    rd_a<1>(lds, 32768, aRowBase, ck0, ck1, a);
    STG(t3e, 2);
    PH(1, 1, b1f, false)
    // P8 (qa1,qb0): no reads; stage B1(t3); vmcnt(6)
    STG(t3e, 3);
    PH(1, 0, b0f, true)
    // A1(t3) staged by next iteration's P1 (buf1.A1 freed at P7).
  }
}

#define ACC_ZERO()                                                             \
  ffrag acc[8][4];                                                             \
  _Pragma("unroll") for (int m = 0; m < 8; ++m)                                \
  _Pragma("unroll") for (int n = 0; n < 4; ++n) acc[m][n] = (ffrag)(0.0f);

// Epilogue mapping for acc[i][j]: qa=i>>2, m=i&3, qb=j>>1, n=j&1.
// row = brow + qa*128 + wr*64 + m*16 + (lane>>4)*4 + r
// col = bcol + qb*128 + wc*32 + n*16 + (lane&15)

// ---------------- kernel 1: qkv projection (V written transposed) ----------
__global__ __launch_bounds__(512, 2) void qkv_gemm256(
    const __bf16* __restrict__ Abf, const __bf16* __restrict__ Wbf,
    const float* __restrict__ bias,
    __bf16* __restrict__ Q, __bf16* __restrict__ Ko, __bf16* __restrict__ Vt) {
  __shared__ __bf16 lds[65536];
  ACC_ZERO();
  int bid = (int)blockIdx.x;
  bid = (bid & 7) * 96 + (bid >> 3);          // XCD swizzle (768 % 8 == 0, bijective)
  const int brow = (bid / 12) * 256;
  const int bcol = (bid % 12) * 256;
  gemm256_mainloop(Abf + (size_t)brow * 1024, Wbf + (size_t)bcol * 1024,
                   1024, 1024, 1024, lds, acc);
  const int lane = threadIdx.x & 63, wid = threadIdx.x >> 6;
  const int wr = wid >> 2, wc = wid & 3;
  const int region = bcol >> 10;              // 0=Q,1=K,2=V (tile within one region)
  if (region < 2) {
    __bf16* dst = region == 0 ? Q : Ko;
    const float scale = region == 0 ? 0.03125f : 1.0f;  // fold 1/sqrt(1024) into Q
#pragma unroll
    for (int j = 0; j < 4; ++j) {
      const int qb = j >> 1, n = j & 1;
      const int col = bcol + qb * 128 + wc * 32 + n * 16 + (lane & 15);
      const int o = col & 1023;
      const float bv = bias[col];
#pragma unroll
      for (int i = 0; i < 8; ++i) {
        const int qa = i >> 2, m = i & 3;
#pragma unroll
        for (int r = 0; r < 4; ++r) {
          const int mg = brow + qa * 128 + wr * 64 + m * 16 + (lane >> 4) * 4 + r;
          dst[(size_t)mg * 1024 + o] = (__bf16)((acc[i][j][r] + bv) * scale);
        }
      }
    }
  } else {
    // V: write transposed Vt[b][d][n]; 4 consecutive n-rows pack into one 8B store
#pragma unroll
    for (int j = 0; j < 4; ++j) {
      const int qb = j >> 1, n = j & 1;
      const int col = bcol + qb * 128 + wc * 32 + n * 16 + (lane & 15);
      const int o = col & 1023;                // d index
      const float bv = bias[col];
#pragma unroll
      for (int i = 0; i < 8; ++i) {
        const int qa = i >> 2, m = i & 3;
        const int mg0 = brow + qa * 128 + wr * 64 + m * 16 + (lane >> 4) * 4;
        const int b = mg0 >> 11, nr = mg0 & 2047;
        bf16x4 v;
#pragma unroll
        for (int r = 0; r < 4; ++r) v[r] = (__bf16)(acc[i][j][r] + bv);
        *(bf16x4*)&Vt[(size_t)b * 2097152 + (size_t)o * 2048 + nr] = v;
      }
    }
  }
}

// ---------------- kernel 2: scores S = Q K^T (Q pre-scaled), bf16 out ------
__global__ __launch_bounds__(512, 2) void scores_gemm256(const __bf16* __restrict__ Q,
                                                         const __bf16* __restrict__ Kb,
                                                         __bf16* __restrict__ S) {
  __shared__ __bf16 lds[65536];
  ACC_ZERO();
  int bid = (int)blockIdx.x;                  // 512 blocks: XCD swizzle, batch-per-XCD
  const int wg = (bid & 7) * 64 + (bid >> 3);
  const int brow = (wg & 7) * 256, bcol = ((wg >> 3) & 7) * 256, z = wg >> 6;
  gemm256_mainloop(Q + (size_t)z * 2048 * 1024 + (size_t)brow * 1024,
                   Kb + (size_t)z * 2048 * 1024 + (size_t)bcol * 1024,
                   1024, 1024, 1024, lds, acc);
  const int lane = threadIdx.x & 63, wid = threadIdx.x >> 6;
  const int wr = wid >> 2, wc = wid & 3;
#pragma unroll
  for (int j = 0; j < 4; ++j) {
    const int qb = j >> 1, n = j & 1;
    const int o = bcol + qb * 128 + wc * 32 + n * 16 + (lane & 15);
#pragma unroll
    for (int i = 0; i < 8; ++i) {
      const int qa = i >> 2, m = i & 3;
#pragma unroll
      for (int r = 0; r < 4; ++r) {
        const int mg = brow + qa * 128 + wr * 64 + m * 16 + (lane >> 4) * 4 + r;
        S[((size_t)(z * 2048 + mg)) * 2048 + o] = (__bf16)acc[i][j][r];
      }
    }
  }
}

// ---------------- kernel 3: in-place bf16 row softmax (wave per row) -------
__global__ __launch_bounds__(256) void softmax_bf16(__bf16* S) {
  const int row = blockIdx.x * 4 + (threadIdx.x >> 6);
  const int lane = threadIdx.x & 63;
  __bf16* s = S + (size_t)row * 2048 + lane * 8;
  float f[32];
#pragma unroll
  for (int c = 0; c < 4; ++c) {
    bf16x8 v = *(const bf16x8*)&s[c * 512];
#pragma unroll
    for (int j = 0; j < 8; ++j) f[c * 8 + j] = (float)v[j];
  }
  float m = f[0];
#pragma unroll
  for (int j = 1; j < 32; ++j) m = fmaxf(m, f[j]);
#pragma unroll
  for (int off = 32; off; off >>= 1) m = fmaxf(m, __shfl_xor(m, off, 64));
  float sum = 0.f;
#pragma unroll
  for (int j = 0; j < 32; ++j) { f[j] = __expf(f[j] - m); sum += f[j]; }
#pragma unroll
  for (int off = 32; off; off >>= 1) sum += __shfl_xor(sum, off, 64);
  const float inv = 1.0f / sum;
#pragma unroll
  for (int c = 0; c < 4; ++c) {
    bf16x8 o;
#pragma unroll
    for (int j = 0; j < 8; ++j) o[j] = (__bf16)(f[c * 8 + j] * inv);
    *(bf16x8*)&s[c * 512] = o;
  }
}

// ---------------- kernel 4: out = P @ V  (via Vt, B^T form) ----------------
__global__ __launch_bounds__(512, 2) void pv_gemm256(const __bf16* __restrict__ P,
                                                     const __bf16* __restrict__ Vt,
                                                     float* __restrict__ O) {
  __shared__ __bf16 lds[65536];
  ACC_ZERO();
  int bid = (int)blockIdx.x;                  // 256 blocks: XCD swizzle, batch-per-XCD
  const int wg = (bid & 7) * 32 + (bid >> 3);
  const int brow = (wg & 7) * 256, bcol = ((wg >> 3) & 3) * 256, z = wg >> 5;
  gemm256_mainloop(P + (size_t)(z * 2048 + brow) * 2048,
                   Vt + (size_t)z * 1024 * 2048 + (size_t)bcol * 2048,
                   2048, 2048, 2048, lds, acc);
  const int lane = threadIdx.x & 63, wid = threadIdx.x >> 6;
  const int wr = wid >> 2, wc = wid & 3;
#pragma unroll
  for (int j = 0; j < 4; ++j) {
    const int qb = j >> 1, n = j & 1;
    const int o = bcol + qb * 128 + wc * 32 + n * 16 + (lane & 15);
#pragma unroll
    for (int i = 0; i < 8; ++i) {
      const int qa = i >> 2, m = i & 3;
#pragma unroll
      for (int r = 0; r < 4; ++r) {
        const int mg = brow + qa * 128 + wr * 64 + m * 16 + (lane >> 4) * 4 + r;
        O[((size_t)(z * 2048 + mg)) * 1024 + o] = acc[i][j][r];
      }
    }
  }
}

extern "C" void kernel_launch(void* const* d_in, const int* in_sizes, int n_in,
                              void* d_out, int out_size, void* d_ws, size_t ws_size,
                              hipStream_t stream) {
  (void)in_sizes; (void)n_in; (void)out_size; (void)ws_size;
  const float* x    = (const float*)d_in[0];
  const float* W    = (const float*)d_in[1];
  const float* bias = (const float*)d_in[2];
  float* out = (float*)d_out;
  char* ws = (char*)d_ws;
  const size_t MB = 1u << 20;
  __bf16* x_bf = (__bf16*)(ws + 0);
  __bf16* W_bf = (__bf16*)(ws + 32 * MB);
  __bf16* Qb   = (__bf16*)(ws + 38 * MB);
  __bf16* Kb   = (__bf16*)(ws + 70 * MB);
  __bf16* S    = (__bf16*)(ws + 102 * MB);   // bf16 scores, softmax in-place -> P
  __bf16* Vt   = (__bf16*)(ws + 166 * MB);   // V^T, written by qkv epilogue

  cvt_f32_bf16<<<2048, 256, 0, stream>>>(x, x_bf, 16777216 / 4);
  cvt_f32_bf16<<<1024, 256, 0, stream>>>(W, W_bf, 3145728 / 4);
  qkv_gemm256<<<768, 512, 0, stream>>>(x_bf, W_bf, bias, Qb, Kb, Vt);
  scores_gemm256<<<512, 512, 0, stream>>>(Qb, Kb, S);
  softmax_bf16<<<4096, 256, 0, stream>>>(S);
  pv_gemm256<<<256, 512, 0, stream>>>(S, Vt, out);
}